// Round 2
// baseline (541.570 us; speedup 1.0000x reference)
//
#include <hip/hip_runtime.h>
#include <stdint.h>
#include <stddef.h>

// SinkhornScorer split-kernel implementation for MI355X (gfx950).
// Kernel 1 (build): one block per batch. Streams x,y once (stats + bf16 pack
//   + MFMA cosine scores), assembles base-2-scaled couplings C2 (37x40 padded)
//   in LDS, stores to d_ws. Register-prefetches the next K-chunk across the
//   MFMA barrier to hide HBM latency.
// Kernel 2 (sink): one WAVE per batch (4 waves/block). Loads C2, transposes via
//   LDS, runs 20 Sinkhorn iterations in registers with per-wave LDS u/v
//   broadcast (no barriers), then writes Z and the <P,S> total.

typedef float  f4  __attribute__((ext_vector_type(4)));
typedef short  s8v __attribute__((ext_vector_type(8)));
typedef unsigned int u2v __attribute__((ext_vector_type(2)));

#define HD   768
#define MR   36          // rows (M == N == 36)
#define KC   128         // K-chunk
#define NCH  6           // 768/128
#define AS   136         // LDS row stride (bf16 elems) for A/B tiles
#define LOG2E 1.4426950408889634f
#define LN2   0.6931471805599453f
#define L272  6.169925001442312f   // log2(72) = -norm_c in base-2
#define KC2   (10.0f*LOG2E)        // couplings scale: /REG then *log2e
#define NEGB  (-1.0e30f)

__device__ __forceinline__ uint32_t pkbf2(float a, float b) {
    uint32_t ua = __float_as_uint(a), ub = __float_as_uint(b);
    ua += 0x7FFFu + ((ua >> 16) & 1u);
    ub += 0x7FFFu + ((ub >> 16) & 1u);
    return (ua >> 16) | (ub & 0xFFFF0000u);
}

// ---------------------------------------------------------------- kernel 1 --
__global__ __launch_bounds__(256, 4) void build_kernel(
    const float* __restrict__ X, const float* __restrict__ Y,
    const float* __restrict__ LG, const float* __restrict__ LB,
    const float* __restrict__ W,  const float* __restrict__ BL,
    float* __restrict__ C2G, int NB)
{
    __shared__ __align__(16) uint16_t Al[48 * AS];   // x bf16 tile
    __shared__ __align__(16) uint16_t Bt[48 * AS];   // y bf16 tile
    __shared__ __align__(16) float Cst[37 * 40];     // couplings staging
    __shared__ float stx[MR * 3], sty[MR * 3];       // per-row {Sx, Sxx, Sxw}
    __shared__ float rnx[MR], rny[MR];               // 1/||row||
    __shared__ float s_gw, s_bw;

    const int t  = threadIdx.x;
    const int b  = blockIdx.x;
    const int wv = t >> 6, ln = t & 63;
    const int c4 = t & 31, gg = t >> 5;

    if (wv == 3) {  // Sgw = sum g*w, Sbw = sum b*w (once)
        float a = 0.0f, c = 0.0f;
        for (int q = 0; q < 12; ++q) {
            int h = ln + 64 * q;
            float wval = W[h];
            a += LG[h] * wval; c += LB[h] * wval;
        }
        for (int o = 32; o > 0; o >>= 1) { a += __shfl_down(a, o); c += __shfl_down(c, o); }
        if (ln == 0) { s_gw = a; s_bw = c; }
    }

    float sx[5][3], sy[5][3];
    #pragma unroll
    for (int p = 0; p < 5; ++p)
        #pragma unroll
        for (int s = 0; s < 3; ++s) { sx[p][s] = 0.0f; sy[p][s] = 0.0f; }

    f4 acc[3];
    #pragma unroll
    for (int i = 0; i < 3; ++i) acc[i] = (f4){0.0f, 0.0f, 0.0f, 0.0f};

    const float* xb = X + (size_t)b * (MR * HD);
    const float* yb = Y + (size_t)b * (MR * HD);

    const int frow = ln & 15, fq = ln >> 4;
    const int rA = (wv * 16 + frow) * AS + fq * 8;

    // register prefetch buffers (chunk k+1 loaded across the MFMA barrier)
    f4 xr[5], yr[5];
    {
        const int k0 = 0;
        #pragma unroll
        for (int p = 0; p < 5; ++p) {
            if (p < 4 || t < 128) {
                const int row = (p < 4) ? (p * 8 + gg) : (32 + gg);
                xr[p] = *(const f4*)(xb + row * HD + k0 + c4 * 4);
                yr[p] = *(const f4*)(yb + row * HD + k0 + c4 * 4);
            }
        }
    }

    for (int kc = 0; kc < NCH; ++kc) {
        const int k0 = kc * KC;
        f4 gv   = *(const f4*)(LG + k0 + c4 * 4);
        f4 wvec = *(const f4*)(W  + k0 + c4 * 4);
        f4 gw = gv * wvec;
        #pragma unroll
        for (int p = 0; p < 5; ++p) {
            if (p < 4 || t < 128) {
                const int row = (p < 4) ? (p * 8 + gg) : (32 + gg);
                f4 xv = xr[p], yv = yr[p];
                sx[p][0] += (xv.x + xv.y) + (xv.z + xv.w);
                sx[p][1] += xv.x * xv.x + xv.y * xv.y + xv.z * xv.z + xv.w * xv.w;
                sx[p][2] += xv.x * gw.x + xv.y * gw.y + xv.z * gw.z + xv.w * gw.w;
                u2v px; px.x = pkbf2(xv.x, xv.y); px.y = pkbf2(xv.z, xv.w);
                *(u2v*)&Al[row * AS + c4 * 4] = px;
                sy[p][0] += (yv.x + yv.y) + (yv.z + yv.w);
                sy[p][1] += yv.x * yv.x + yv.y * yv.y + yv.z * yv.z + yv.w * yv.w;
                sy[p][2] += yv.x * gw.x + yv.y * gw.y + yv.z * gw.z + yv.w * gw.w;
                u2v py; py.x = pkbf2(yv.x, yv.y); py.y = pkbf2(yv.z, yv.w);
                *(u2v*)&Bt[row * AS + c4 * 4] = py;
            }
        }
        __syncthreads();
        if (kc < NCH - 1) {   // issue next-chunk loads; latency hides under MFMA
            const int k1 = k0 + KC;
            #pragma unroll
            for (int p = 0; p < 5; ++p) {
                if (p < 4 || t < 128) {
                    const int row = (p < 4) ? (p * 8 + gg) : (32 + gg);
                    xr[p] = *(const f4*)(xb + row * HD + k1 + c4 * 4);
                    yr[p] = *(const f4*)(yb + row * HD + k1 + c4 * 4);
                }
            }
        }
        if (wv < 3) {
            #pragma unroll
            for (int ks = 0; ks < 4; ++ks) {
                s8v af = *(const s8v*)&Al[rA + ks * 32];
                #pragma unroll
                for (int tn = 0; tn < 3; ++tn) {
                    s8v bf = *(const s8v*)&Bt[(tn * 16 + frow) * AS + fq * 8 + ks * 32];
                    acc[tn] = __builtin_amdgcn_mfma_f32_16x16x32_bf16(af, bf, acc[tn], 0, 0, 0);
                }
            }
        }
        __syncthreads();
    }

    // ---- stats reduction: 32-lane groups own fixed rows ----
    #pragma unroll
    for (int p = 0; p < 5; ++p) {
        const int row = (p < 4) ? (p * 8 + gg) : (32 + gg);
        #pragma unroll
        for (int s = 0; s < 3; ++s) {
            float a = sx[p][s], c = sy[p][s];
            for (int o = 16; o > 0; o >>= 1) { a += __shfl_down(a, o, 32); c += __shfl_down(c, o, 32); }
            if ((t & 31) == 0 && row < MR) { stx[row * 3 + s] = a; sty[row * 3 + s] = c; }
        }
    }
    __syncthreads();

    // ---- derived per-row: 1/norm, dustbin scores, pads, corner ----
    {
        const float blin = BL[0];
        if (t < MR) {
            float Sx = stx[t * 3], Sxx = stx[t * 3 + 1], Sxw = stx[t * 3 + 2];
            rnx[t] = __builtin_amdgcn_rsqf(Sxx);
            float mu  = Sx * (1.0f / HD);
            float var = Sxx * (1.0f / HD) - mu * mu;
            float rsd = __builtin_amdgcn_rsqf(var + 1e-5f);
            float lin = (Sxw - mu * s_gw) * rsd + s_bw + blin;
            float e   = __builtin_amdgcn_exp2f(2.0f * LOG2E * lin);
            float th  = (e - 1.0f) / (e + 1.0f);
            Cst[t * 40 + 36] = th * KC2;
        } else if (t >= 64 && t < 64 + MR) {
            int j = t - 64;
            float Sy = sty[j * 3], Syy = sty[j * 3 + 1], Syw = sty[j * 3 + 2];
            rny[j] = __builtin_amdgcn_rsqf(Syy);
            float mu  = Sy * (1.0f / HD);
            float var = Syy * (1.0f / HD) - mu * mu;
            float rsd = __builtin_amdgcn_rsqf(var + 1e-5f);
            float lin = (Syw - mu * s_gw) * rsd + s_bw + blin;
            float e   = __builtin_amdgcn_exp2f(2.0f * LOG2E * lin);
            float th  = (e - 1.0f) / (e + 1.0f);
            Cst[36 * 40 + j] = th * KC2;
        } else if (t == 128) {
            Cst[36 * 40 + 36] = -100.0f * KC2;   // ALPHA_BOTH/REG in base-2
        }
        if (t >= 160 && t < 160 + 37) {
            int i = t - 160;
            Cst[i * 40 + 37] = NEGB; Cst[i * 40 + 38] = NEGB; Cst[i * 40 + 39] = NEGB;
        }
    }
    __syncthreads();

    // ---- scores -> couplings (base-2) ----
    if (wv < 3) {
        #pragma unroll
        for (int tn = 0; tn < 3; ++tn) {
            #pragma unroll
            for (int r = 0; r < 4; ++r) {
                int i = wv * 16 + fq * 4 + r;
                int j = tn * 16 + frow;
                if (i < MR && j < MR)
                    Cst[i * 40 + j] = acc[tn][r] * rnx[i] * rny[j] * KC2;
            }
        }
    }
    __syncthreads();

    // ---- store C2 to workspace (coalesced f4) ----
    {
        f4* dst = (f4*)(C2G + (size_t)b * 1480);
        const f4* src = (const f4*)Cst;
        for (int q = t; q < 370; q += 256) dst[q] = src[q];
    }
}

// ---------------------------------------------------------------- kernel 2 --
__global__ __launch_bounds__(256, 2) void sink_kernel(
    const float* __restrict__ C2G, float* __restrict__ OUT, int NB)
{
    __shared__ __align__(16) float Cl[4][1480];
    __shared__ __align__(16) float ub[4][40];
    __shared__ __align__(16) float vb[4][40];

    const int t = threadIdx.x, wv = t >> 6, ln = t & 63;
    const int b = blockIdx.x * 4 + wv;
    if (b >= NB) return;                    // no barriers in this kernel

    float* Cw = &Cl[wv][0];
    {   // stage this wave's C2 into LDS
        const f4* src = (const f4*)(C2G + (size_t)b * 1480);
        f4* dst = (f4*)Cw;
        for (int q = ln; q < 370; q += 64) dst[q] = src[q];
    }
    if (ln < 40) { ub[wv][ln] = 0.0f; vb[wv][ln] = 0.0f; }

    const int r = (ln < 37) ? ln : 36;      // clamped row for lanes 37..63
    f4 cr[10];                               // row r of C
    float ct[40];                            // col r of C  (row r of C^T)
    #pragma unroll
    for (int jj = 0; jj < 10; ++jj) cr[jj] = *(const f4*)&Cw[r * 40 + jj * 4];
    #pragma unroll
    for (int j = 0; j < 37; ++j) ct[j] = Cw[j * 40 + r];
    ct[37] = NEGB; ct[38] = NEGB; ct[39] = NEGB;

    const float lmu = (ln < 36) ? -L272 : -1.0f;  // log2 marginals (mu == nu)

    for (int it = 0; it < 20; ++it) {
        float tt[40];
        float m = -3.0e38f;
        #pragma unroll
        for (int jj = 0; jj < 10; ++jj) {
            f4 vv = *(const f4*)&vb[wv][jj * 4];
            f4 s = cr[jj] + vv;
            tt[jj*4+0] = s.x; tt[jj*4+1] = s.y; tt[jj*4+2] = s.z; tt[jj*4+3] = s.w;
            m = fmaxf(m, fmaxf(fmaxf(s.x, s.y), fmaxf(s.z, s.w)));
        }
        float ss = 0.0f;
        #pragma unroll
        for (int k = 0; k < 40; ++k) ss += __builtin_amdgcn_exp2f(tt[k] - m);
        if (ln < 37) ub[wv][ln] = lmu - (m + __builtin_amdgcn_logf(ss));

        m = -3.0e38f;
        #pragma unroll
        for (int jj = 0; jj < 10; ++jj) {
            f4 uu = *(const f4*)&ub[wv][jj * 4];
            f4 cv = *(const f4*)&ct[jj * 4];
            f4 s = cv + uu;
            tt[jj*4+0] = s.x; tt[jj*4+1] = s.y; tt[jj*4+2] = s.z; tt[jj*4+3] = s.w;
            m = fmaxf(m, fmaxf(fmaxf(s.x, s.y), fmaxf(s.z, s.w)));
        }
        ss = 0.0f;
        #pragma unroll
        for (int k = 0; k < 40; ++k) ss += __builtin_amdgcn_exp2f(tt[k] - m);
        if (ln < 37) vb[wv][ln] = lmu - (m + __builtin_amdgcn_logf(ss));
    }

    // ---- epilogue: Z write + total = <exp(Z), scores>/TEMP ----
    float tot = 0.0f;
    const size_t ob = (size_t)b * 1369;
    for (int e = ln; e < 1369; e += 64) {
        int i = e / 37, j = e - i * 37;
        float c2v = Cw[i * 40 + j];
        float z2  = c2v + ub[wv][i] + vb[wv][j] + L272;
        OUT[ob + e] = z2 * LN2;
        if (i < MR && j < MR)
            tot += __builtin_amdgcn_exp2f(z2) * (c2v * (0.1f * LN2));
    }
    for (int o = 32; o > 0; o >>= 1) tot += __shfl_down(tot, o);
    if (ln == 0) OUT[(size_t)NB * 1369 + b] = tot * 10.0f;   // /TEMP
}

extern "C" void kernel_launch(void* const* d_in, const int* in_sizes, int n_in,
                              void* d_out, int out_size, void* d_ws, size_t ws_size,
                              hipStream_t stream) {
    const float* X  = (const float*)d_in[0];
    const float* Y  = (const float*)d_in[1];
    const float* LG = (const float*)d_in[2];
    const float* LB = (const float*)d_in[3];
    const float* W  = (const float*)d_in[4];
    const float* BL = (const float*)d_in[5];
    const int NB = in_sizes[0] / (MR * HD);   // 2048
    float* C2G = (float*)d_ws;                // 2048 * 1480 * 4 B = 12.1 MB
    hipLaunchKernelGGL(build_kernel, dim3(NB), dim3(256), 0, stream,
                       X, Y, LG, LB, W, BL, C2G, NB);
    hipLaunchKernelGGL(sink_kernel, dim3((NB + 3) / 4), dim3(256), 0, stream,
                       C2G, (float*)d_out, NB);
}